// Round 13
// baseline (80.721 us; speedup 1.0000x reference)
//
#include <hip/hip_runtime.h>
#include <hip/hip_bf16.h>

#define HH 512
#define BB 8192
#define KK 1536
#define NT 48              // 32-k blobs per panel
#define NT2 24             // K-64 tiles
#define HB 4194304         // 512*8192
#define BLOB 8192          // bhalf per 16KB blob

typedef __bf16 bhalf;
typedef __bf16 bf16x8 __attribute__((ext_vector_type(8)));
typedef float  f32x4  __attribute__((ext_vector_type(4)));

typedef __attribute__((address_space(1))) void* as1_t;
typedef __attribute__((address_space(3))) void* as3_t;

#define GLDS(src, dst) __builtin_amdgcn_global_load_lds((as1_t)(void*)(src), (as3_t)(void*)(dst), 16, 0, 0)
#define SBAR() asm volatile("s_barrier" ::: "memory")
#define VM8()  asm volatile("s_waitcnt vmcnt(8)" ::: "memory")
#define VM4()  asm volatile("s_waitcnt vmcnt(4)" ::: "memory")
#define VM0()  asm volatile("s_waitcnt vmcnt(0)" ::: "memory")

// Packed blob layout (k-major, conflict-free, verified R4): blob = 256 rows x
// 32 k = 16 KB; slot s = rb*64 + hi*16 + lr; element (row rb*16+lr, k hi*8+e)
// at bhalf offset s*8+e.  Fragment read offset: rb*512 + hi*128 + lr*8.

// ---------------------------------------------------------------------------
// prep_all: blocks 0..1535 = prep_x (+ z_hat partials); 1536..2047 = prep_w.
// (R12 verbatim.)
// ---------------------------------------------------------------------------
__global__ __launch_bounds__(256) void prep_all(
    const float* __restrict__ h, const float* __restrict__ ht,
    const float* __restrict__ hb, const float* __restrict__ z,
    const float* __restrict__ zb, const float* __restrict__ U11,
    const float* __restrict__ U21, const float* __restrict__ W01,
    bhalf* __restrict__ XtP, bhalf* __restrict__ WcP,
    float* __restrict__ zpart)
{
    const int tid = threadIdx.x;
    const int b   = blockIdx.x;

    if (b < 1536) {
        __shared__ float tile[32][257];
        const int kt = b % 48;
        const int nt = b / 48;
        const int n  = nt * 256 + tid;
        const int kb = kt * 32;

        const float* src; const float* wsrc; int kr; float scale;
        if (kb < 512)       { src = h;  wsrc = U11 + (size_t)2048 * 512 + kb;
                              kr = kb;        scale = 1.f - z[n]; }
        else if (kb < 1024) { src = ht; wsrc = U21 + (size_t)2048 * 512 + (kb - 512);
                              kr = kb - 512;  scale = z[n]; }
        else                { src = hb; wsrc = W01 + (size_t)2048 * 512 + (kb - 1024);
                              kr = kb - 1024; scale = zb[n]; }

        float zp = 0.f;
        #pragma unroll
        for (int kk = 0; kk < 32; ++kk) {
            const float v = src[(size_t)(kr + kk) * BB + n] * scale;
            tile[kk][tid] = v;
            zp += v * wsrc[kk];
        }
        zpart[(size_t)kt * BB + n] = zp;
        __syncthreads();

        bhalf* blob = XtP + (size_t)(nt * NT + kt) * BLOB;
        #pragma unroll
        for (int q = 0; q < 4; ++q) {
            const int s  = q * 256 + tid;
            const int rb = s >> 6, w = s & 63;
            const int hh = w >> 4, lrr = w & 15;
            const int nloc = rb * 16 + lrr, kloc = hh * 8;
            bf16x8 r;
            #pragma unroll
            for (int e = 0; e < 8; ++e) r[e] = (bhalf)tile[kloc + e][nloc];
            *(bf16x8*)(blob + s * 8) = r;
        }
    } else {
        const int o    = (b - 1536) * 4 + (tid >> 6);
        const int lane = tid & 63;
        const int g = o >> 9, j = o & 511;
        const int mp = 4 * j + g;
        const int mt = mp >> 8, rb = (mp >> 4) & 15, lrr = mp & 15;

        #pragma unroll
        for (int p = 0; p < 3; ++p) {
            const float* src = (p == 0) ? U11 : (p == 1) ? U21 : W01;
            const float* rp  = src + (size_t)o * 512 + lane * 8;
            float4 v0 = *(const float4*)rp;
            float4 v1 = *(const float4*)(rp + 4);
            bf16x8 r;
            r[0]=(bhalf)v0.x; r[1]=(bhalf)v0.y; r[2]=(bhalf)v0.z; r[3]=(bhalf)v0.w;
            r[4]=(bhalf)v1.x; r[5]=(bhalf)v1.y; r[6]=(bhalf)v1.z; r[7]=(bhalf)v1.w;
            const int kt = p * 16 + (lane >> 2);
            const int hh = lane & 3;
            *(bf16x8*)(WcP + (size_t)(mt * NT + kt) * BLOB
                       + rb * 512 + hh * 128 + lrr * 8) = r;
        }
    }
}

// ---------------------------------------------------------------------------
__device__ __forceinline__ float sigmf(float x)    { return 1.f / (1.f + __expf(-x)); }
__device__ __forceinline__ float tanhfast(float x) { return 2.f / (1.f + __expf(-2.f * x)) - 1.f; }

// ---------------------------------------------------------------------------
// gemm_fused: m201-style 8-phase schedule.  BM=BN=256, BK=64, 8 waves
// (2M x 4N, wave tile 128x64), LDS = 2buf x 2khalf x (A 16KB + B 16KB)
// = 128 KB, 1 block/CU (grid 256).  4 phases per K-64 tile:
//   P0 (m0,k0): read A m0..3 + B (kh0), stage(t+1,kh0), bar, 16 MFMA, bar
//   P1 (m1,k0): read A m4..7,           stage(t+1,kh1), vmcnt(8), bar, MFMA, bar
//   P2 (m0,k1): read A m0..3 + B (kh1),                 bar, MFMA, bar
//   P3 (m1,k1): read A m4..7,                 vmcnt(4), bar, MFMA, bar
// Counted vmcnt BEFORE the barrier guarding the next phase's reads of fresh
// LDS (cross-wave safe); never drains to 0 in steady state.
// z_hat finalize at kernel top, sealed with vmcnt(0) so its global ops don't
// perturb the counted-vmcnt arithmetic.
// ---------------------------------------------------------------------------
__global__ __launch_bounds__(512, 2) void gemm_fused(
    const bhalf* __restrict__ WcP, const bhalf* __restrict__ XtP,
    const float* __restrict__ bias, const float* __restrict__ c_in,
    const float* __restrict__ h_in, const float* __restrict__ z,
    const float* __restrict__ zb, const float* __restrict__ zpart,
    float* __restrict__ out)
{
    __shared__ bhalf As[2][2][BLOB];     // [buf][khalf] 4 x 16 KB
    __shared__ bhalf Bs[2][2][BLOB];     // [buf][khalf] 4 x 16 KB

    const int tid  = threadIdx.x;
    const int lane = tid & 63;
    const int wid  = tid >> 6;          // 0..7
    const int wm   = wid >> 2, wn = wid & 3;   // 2M x 4N, wave tile 128x64
    const int lr   = lane & 15, hi = lane >> 4;
    const int soff = hi * 128 + lr * 8;

    const int xcd = blockIdx.x & 7;
    const int i   = blockIdx.x >> 3;          // 0..31
    const int mt  = i & 7;                    // 0..7
    const int nt  = xcd * 4 + (i >> 3);       // 0..31
    const int m0 = mt * 256, n0 = nt * 256;

    // ---- z_hat finalize first (sealed): waves 0..3 of mt==0 blocks ----
    if (mt == 0 && tid < 256) {
        const int n = n0 + tid;
        float s = 0.f;
        #pragma unroll
        for (int kt2 = 0; kt2 < NT; ++kt2) s += zpart[(size_t)kt2 * BB + n];
        const float v = (s + bias[2048] + 1.f) * 0.5f;
        out[(size_t)2 * HB + n] = fminf(fmaxf(v, 0.f), 1.f);
        VM0();                           // retire before counted staging
    }

    const bhalf* gA = WcP + (size_t)mt * (NT * BLOB) + tid * 8;
    const bhalf* gB = XtP + (size_t)nt * (NT * BLOB) + tid * 8;

    const bhalf* pa00 = &As[0][0][wm * 4096 + soff];
    const bhalf* pa01 = &As[0][1][wm * 4096 + soff];
    const bhalf* pa10 = &As[1][0][wm * 4096 + soff];
    const bhalf* pa11 = &As[1][1][wm * 4096 + soff];
    const bhalf* pb00 = &Bs[0][0][wn * 2048 + soff];
    const bhalf* pb01 = &Bs[0][1][wn * 2048 + soff];
    const bhalf* pb10 = &Bs[1][0][wn * 2048 + soff];
    const bhalf* pb11 = &Bs[1][1][wn * 2048 + soff];

// stage one k-half of tile t2 into buf nb: A 2 loads + B 2 loads per thread
#define STG(t2, kh, nb) do {                                                  \
        const bhalf* sa_ = gA + (size_t)((t2) * 2 + (kh)) * BLOB;             \
        const bhalf* sb_ = gB + (size_t)((t2) * 2 + (kh)) * BLOB;             \
        GLDS(sa_,        &As[nb][kh][tid * 8]);                               \
        GLDS(sa_ + 4096, &As[nb][kh][tid * 8 + 4096]);                        \
        GLDS(sb_,        &Bs[nb][kh][tid * 8]);                               \
        GLDS(sb_ + 4096, &Bs[nb][kh][tid * 8 + 4096]);                        \
    } while (0)

#define MF(mi, ni, A_, B_) acc[mi][ni] = \
    __builtin_amdgcn_mfma_f32_16x16x32_bf16(A_, B_, acc[mi][ni], 0, 0, 0)

// 16-MFMA cluster: acc rows mb..mb+3, all 4 n, from a0..a3/b0..b3
#define CL(mb) do { __builtin_amdgcn_s_setprio(1);                            \
    MF(mb+0,0,a0,b0); MF(mb+0,1,a0,b1); MF(mb+0,2,a0,b2); MF(mb+0,3,a0,b3);   \
    MF(mb+1,0,a1,b0); MF(mb+1,1,a1,b1); MF(mb+1,2,a1,b2); MF(mb+1,3,a1,b3);   \
    MF(mb+2,0,a2,b0); MF(mb+2,1,a2,b1); MF(mb+2,2,a2,b2); MF(mb+2,3,a2,b3);   \
    MF(mb+3,0,a3,b0); MF(mb+3,1,a3,b1); MF(mb+3,2,a3,b2); MF(mb+3,3,a3,b3);   \
    __builtin_amdgcn_s_setprio(0); } while (0)

#define RDA4(P, off) do {                                                     \
    a0 = *(const bf16x8*)(P + (off));        a1 = *(const bf16x8*)(P + (off) + 512);  \
    a2 = *(const bf16x8*)(P + (off) + 1024); a3 = *(const bf16x8*)(P + (off) + 1536); } while (0)
#define RDB4(P) do {                                                          \
    b0 = *(const bf16x8*)(P);        b1 = *(const bf16x8*)(P + 512);          \
    b2 = *(const bf16x8*)(P + 1024); b3 = *(const bf16x8*)(P + 1536); } while (0)

// one K-64 tile in buf B_ (staging tile TS into buf NB_ when DOST)
#define TILE(AB0, AB1, BB0, BB1, NB_, TS, DOST, VMP1, VMP3) do {              \
    /* P0: (m0,k0) */                                                         \
    RDB4(BB0); RDA4(AB0, 0);                                                  \
    if (DOST) STG(TS, 0, NB_);                                                \
    SBAR(); CL(0); SBAR();                                                    \
    /* P1: (m1,k0) — b regs held */                                           \
    RDA4(AB0, 2048);                                                          \
    if (DOST) STG(TS, 1, NB_);                                                \
    VMP1; SBAR(); CL(4); SBAR();                                              \
    /* P2: (m0,k1) */                                                         \
    RDB4(BB1); RDA4(AB1, 0);                                                  \
    SBAR(); CL(0); SBAR();                                                    \
    /* P3: (m1,k1) */                                                         \
    RDA4(AB1, 2048);                                                          \
    VMP3; SBAR(); CL(4); SBAR();                                              \
} while (0)

    f32x4 acc[8][4] = {};
    bf16x8 a0, a1, a2, a3, b0, b1, b2, b3;

    // prologue: stage tile 0 (both k-halves); wait kh0 chip-wide
    STG(0, 0, 0); STG(0, 1, 0);
    VM4(); SBAR();

    // steady state: tiles 0..21 (pairs), each stages t+1 into other buf
    for (int t = 0; t < 22; t += 2) {
        TILE(pa00, pa01, pb00, pb01, 1, t + 1, 1, VM8(), VM4());
        TILE(pa10, pa11, pb10, pb11, 0, t + 2, 1, VM8(), VM4());
    }
    // tile 22 (buf0): stage 23 into buf1
    TILE(pa00, pa01, pb00, pb01, 1, 23, 1, VM8(), VM4());
    // tile 23 (buf1): no staging; P1 drains kh1
    TILE(pa10, pa11, pb10, pb11, 0, 0, 0, VM0(), ((void)0));

    // ---- fused gate epilogue: acc[mi][ni][r] = gate r of hidden j ----
    const int colbase = n0 + wn * 64 + lr;
    float zc[4], zbc[4];
    #pragma unroll
    for (int ni = 0; ni < 4; ++ni) {
        zc[ni]  = z[colbase + ni * 16];
        zbc[ni] = zb[colbase + ni * 16];
    }
    #pragma unroll
    for (int mi = 0; mi < 8; ++mi) {
        const int j = (m0 >> 2) + wm * 32 + mi * 4 + hi;
        const float bf_ = bias[j];
        const float bi_ = bias[512 + j];
        const float bo_ = bias[1024 + j];
        const float bg_ = bias[1536 + j];
        #pragma unroll
        for (int ni = 0; ni < 4; ++ni) {
            const int col = colbase + ni * 16;
            const size_t idx = (size_t)j * BB + col;
            const float cv = c_in[idx];
            const float hv = h_in[idx];
            const float fv = sigmf(acc[mi][ni][0] + bf_);
            const float iv = sigmf(acc[mi][ni][1] + bi_);
            const float ov = sigmf(acc[mi][ni][2] + bo_);
            const float gv = tanhfast(acc[mi][ni][3] + bg_);
            const float ig = iv * gv;
            const float zq = zc[ni], zbq = zbc[ni];
            const float cn = zq * ig + (1.f - zq) * (1.f - zbq) * cv
                           + (1.f - zq) * zbq * (fv * cv + ig);
            const float tc = tanhfast(cn);
            const float hn = (zq + (1.f - zq) * zbq) * ov * tc
                           + (1.f - zq) * (1.f - zbq) * hv;
            out[idx]      = hn;
            out[HB + idx] = cn;
        }
    }
}

// ---------------------------------------------------------------------------
extern "C" void kernel_launch(void* const* d_in, const int* in_sizes, int n_in,
                              void* d_out, int out_size, void* d_ws, size_t ws_size,
                              hipStream_t stream) {
    const float* c    = (const float*)d_in[0];
    const float* hb   = (const float*)d_in[1];
    const float* h    = (const float*)d_in[2];
    const float* ht   = (const float*)d_in[3];
    const float* z    = (const float*)d_in[4];
    const float* zb   = (const float*)d_in[5];
    const float* U11  = (const float*)d_in[6];
    const float* U21  = (const float*)d_in[7];
    const float* W01  = (const float*)d_in[8];
    const float* bias = (const float*)d_in[9];
    float* out = (float*)d_out;

    char* ws = (char*)d_ws;
    bhalf* XtP   = (bhalf*)ws;                     // 32*48*16KB = 25165824 B
    bhalf* WcP   = (bhalf*)(ws + 25165824);        //  8*48*16KB =  6291456 B
    float* zpart = (float*)(ws + 25165824 + 6291456);  // 48*8192*4 = 1572864 B

    prep_all  <<<2048, 256, 0, stream>>>(h, ht, hb, z, zb, U11, U21, W01,
                                         XtP, WcP, zpart);
    gemm_fused<<<256, 512, 0, stream>>>(WcP, XtP, bias, c, h, z, zb,
                                        zpart, out);
}